// Round 2
// baseline (930.612 us; speedup 1.0000x reference)
//
#include <hip/hip_runtime.h>

#define NNODES 1700
#define CDIM   256

typedef __attribute__((ext_vector_type(8))) short bf16x8;
typedef __attribute__((ext_vector_type(4))) float f32x4;

__device__ inline float bf2f(unsigned h) { return __uint_as_float(h << 16); }
__device__ inline unsigned short f2bf(float f) {
  unsigned u = __float_as_uint(f);
  u = (u + 0x7FFFu + ((u >> 16) & 1u)) >> 16;  // RNE
  return (unsigned short)u;
}

__device__ inline void async_copy16(const void* gsrc, void* ldst) {
  __builtin_amdgcn_global_load_lds(
      (const __attribute__((address_space(1))) unsigned int*)gsrc,
      (__attribute__((address_space(3))) unsigned int*)ldst,
      16, 0, 0);
}

// ---------------- graph preprocessing ----------------

__global__ void zero_kernel(int* p, int n) {
  int i = blockIdx.x * blockDim.x + threadIdx.x;
  if (i < n) p[i] = 0;
}

// edge_index layout [2, E] row-major: sources [0..E), destinations [E..2E)
__global__ void count_kernel(const int* __restrict__ ei, int E, int* __restrict__ cnt) {
  int i = blockIdx.x * blockDim.x + threadIdx.x;
  if (i < E) atomicAdd(&cnt[ei[E + i]], 1);
}

__global__ void dinv_kernel(const int* __restrict__ cnt, float* __restrict__ dinv, int n) {
  int i = blockIdx.x * blockDim.x + threadIdx.x;
  if (i < n) dinv[i] = rsqrtf((float)(cnt[i] + 1));  // +1 self-loop; deg >= 1
}

// exclusive scan of (cnt[i]+1) over N=1700 -> off[0..N]; single block, 1024 thr, 2048 slots
__global__ __launch_bounds__(1024) void scan_kernel(const int* __restrict__ cnt, int n,
                                                    int* __restrict__ off) {
  __shared__ int s[2048];
  int t = threadIdx.x;
  for (int i = t; i < 2048; i += 1024) s[i] = (i < n) ? (cnt[i] + 1) : 0;
  for (int d = 1; d < 2048; d <<= 1) {
    __syncthreads();
    int idx = (t + 1) * (d << 1) - 1;
    if (idx < 2048) s[idx] += s[idx - d];
  }
  __syncthreads();
  if (t == 0) s[2047] = 0;
  for (int d = 1024; d >= 1; d >>= 1) {
    __syncthreads();
    int idx = (t + 1) * (d << 1) - 1;
    if (idx < 2048) { int tmp = s[idx - d]; s[idx - d] = s[idx]; s[idx] += tmp; }
  }
  __syncthreads();
  for (int i = t; i <= n; i += 1024) off[i] = s[i];
}

__global__ void fill_kernel(const int* __restrict__ ei, int E, int n,
                            const float* __restrict__ dinv, const int* __restrict__ off,
                            int* __restrict__ cursor, int* __restrict__ srcv,
                            float* __restrict__ wv) {
  int i = blockIdx.x * blockDim.x + threadIdx.x;
  if (i >= E + n) return;
  int s, d;
  if (i < E) { s = ei[i]; d = ei[E + i]; } else { s = d = i - E; }
  float w = dinv[s] * dinv[d];
  int p = atomicAdd(&cursor[d], 1);
  int idx = off[d] + p;
  srcv[idx] = s;
  wv[idx] = w;
}

// W f32 [k][n] row-major -> Wt bf16 [n][k]
__global__ void transpose_kernel(const float* __restrict__ W,
                                 unsigned short* __restrict__ Wt) {
  int i = blockIdx.x * 256 + threadIdx.x;  // 65536 elems
  int k = i >> 8, n = i & 255;
  Wt[n * 256 + k] = f2bf(W[i]);
}

// ---------------- fused GCN layer: out = epilogue( (A_hat @ X) @ W ) ------------------------
// Associativity: A_hat(XW) = (A_hat X)W. Per block: build 64 aggregated A-rows in LDS via
// edge gathers (f32 accumulate), then 128x... 64x256 MFMA GEMM vs Wt with counted-vmcnt
// 3-buffer pipeline (round-1 proven template). Epilogue: +bias, (+resid), relu, store.
// Grid M/64, 256 threads = 4 waves; wave w owns 64x64 output quadrant (cols w*64..).
// LDS: As [8][64][32] 32KB + Bs 3x16KB = 80KB exactly -> 2 blocks/CU.

template <int K>
__device__ __forceinline__ void kstep(const unsigned short* __restrict__ Wt,
                                      const unsigned short (&As)[8 * 2048],
                                      unsigned short (&Bs)[3][256 * 32],
                                      int t, int wn, int lr, int lk,
                                      f32x4 (&acc)[4][4]) {
  // stage K's 4 loads issued 2 steps ago; leave stage K+1's 4 in flight
  if constexpr (K < 7) {
    asm volatile("s_waitcnt vmcnt(4)" ::: "memory");
  } else {
    asm volatile("s_waitcnt vmcnt(0)" ::: "memory");
  }
  __builtin_amdgcn_s_barrier();  // raw barrier: no auto vmcnt(0) drain
  if constexpr (K + 2 < 8) {
    constexpr int S = K + 2;
#pragma unroll
    for (int j = 0; j < 4; j++) {
      int c = t + 256 * j;  // 16B chunk: B-row c>>2, k-slot (c&3)*8
      async_copy16(Wt + (size_t)(c >> 2) * CDIM + S * 32 + (c & 3) * 8,
                   &Bs[S % 3][c * 8]);
    }
  }
  bf16x8 a[4], b[4];
#pragma unroll
  for (int i = 0; i < 4; i++)
    a[i] = *(const bf16x8*)&As[K * 2048 + (i * 16 + lr) * 32 + lk];
#pragma unroll
  for (int i = 0; i < 4; i++)
    b[i] = *(const bf16x8*)&Bs[K % 3][(wn + i * 16 + lr) * 32 + lk];
#pragma unroll
  for (int mi = 0; mi < 4; mi++)
#pragma unroll
    for (int ni = 0; ni < 4; ni++)
      acc[mi][ni] = __builtin_amdgcn_mfma_f32_16x16x32_bf16(a[mi], b[ni], acc[mi][ni], 0, 0, 0);
}

template <bool AF32, bool FINAL>
__global__ __launch_bounds__(256, 2) void fused_layer(
    const void* __restrict__ Ap,            // X_prev: f32 [B,N,C] if AF32 else bf16
    const unsigned short* __restrict__ Wt,  // bf16 W^T [n][k]
    const int* __restrict__ off, const int* __restrict__ srcv,
    const float* __restrict__ wv, const float* __restrict__ bias,
    const float* __restrict__ resid,        // f32, FINAL only
    void* __restrict__ outp) {              // bf16 [M][C] or f32 (FINAL)
  __shared__ __align__(16) unsigned short As[8 * 2048];    // [kchunk][row][32] 32 KB
  __shared__ __align__(16) unsigned short Bs[3][256 * 32]; // 48 KB
  const int t = threadIdx.x;
  const int lane = t & 63;
  const int w = t >> 6;
  const int m0 = blockIdx.x * 64;
  const int wn = w * 64;
  const int lr = lane & 15;
  const int lk = (lane >> 4) * 8;

  // prologue: Bs stages 0,1 in flight (overlap with A-build gathers)
#pragma unroll
  for (int st = 0; st < 2; st++)
#pragma unroll
    for (int j = 0; j < 4; j++) {
      int c = t + 256 * j;
      async_copy16(Wt + (size_t)(c >> 2) * CDIM + st * 32 + (c & 3) * 8, &Bs[st][c * 8]);
    }

  // ---- A-build: one row per wave (uniform edge loop), 4 channels per lane ----
  const int cc = lane * 4;
  for (int rr = 0; rr < 16; rr++) {
    const int row = rr * 4 + w;
    const int m = m0 + row;
    const int b = m / NNODES;
    const int n = m - b * NNODES;
    const int beg = off[n], end = off[n + 1];
    const size_t base = (size_t)b * NNODES;
    float c0 = 0.f, c1 = 0.f, c2 = 0.f, c3 = 0.f;
    if (AF32) {
      const float* X = (const float*)Ap;
      for (int i = beg; i < end; i++) {
        int sv = srcv[i];
        float wt = wv[i];
        float4 v = *(const float4*)(X + (base + sv) * CDIM + cc);
        c0 += wt * v.x; c1 += wt * v.y; c2 += wt * v.z; c3 += wt * v.w;
      }
    } else {
      const unsigned short* X = (const unsigned short*)Ap;
      for (int i = beg; i < end; i++) {
        int sv = srcv[i];
        float wt = wv[i];
        uint2 v = *(const uint2*)(X + (base + sv) * CDIM + cc);
        c0 += wt * bf2f(v.x & 0xffffu); c1 += wt * bf2f(v.x >> 16);
        c2 += wt * bf2f(v.y & 0xffffu); c3 += wt * bf2f(v.y >> 16);
      }
    }
    uint2 o;
    o.x = (unsigned)f2bf(c0) | ((unsigned)f2bf(c1) << 16);
    o.y = (unsigned)f2bf(c2) | ((unsigned)f2bf(c3) << 16);
    *(uint2*)&As[(cc >> 5) * 2048 + row * 32 + (cc & 31)] = o;
  }
  __syncthreads();  // drains gathers + prologue stages + As ds_writes

  f32x4 acc[4][4] = {};
  kstep<0>(Wt, As, Bs, t, wn, lr, lk, acc);
  kstep<1>(Wt, As, Bs, t, wn, lr, lk, acc);
  kstep<2>(Wt, As, Bs, t, wn, lr, lk, acc);
  kstep<3>(Wt, As, Bs, t, wn, lr, lk, acc);
  kstep<4>(Wt, As, Bs, t, wn, lr, lk, acc);
  kstep<5>(Wt, As, Bs, t, wn, lr, lk, acc);
  kstep<6>(Wt, As, Bs, t, wn, lr, lk, acc);
  kstep<7>(Wt, As, Bs, t, wn, lr, lk, acc);

  // ---- epilogue ----
  float bv[4];
#pragma unroll
  for (int ni = 0; ni < 4; ni++) bv[ni] = bias[wn + ni * 16 + lr];
  const int orow = (lane >> 4) * 4;  // C/D: col=lane&15, row=(lane>>4)*4+r  [m89/m91]
#pragma unroll
  for (int mi = 0; mi < 4; mi++) {
#pragma unroll
    for (int r = 0; r < 4; r++) {
      const size_t gr = (size_t)(m0 + mi * 16 + orow + r);
      if (FINAL) {
        float* O = (float*)outp;
#pragma unroll
        for (int ni = 0; ni < 4; ni++) {
          const size_t idx = gr * CDIM + wn + ni * 16 + lr;
          float v = acc[mi][ni][r] + bv[ni] + resid[idx];
          O[idx] = fmaxf(v, 0.f);
        }
      } else {
        unsigned short* O = (unsigned short*)outp;
#pragma unroll
        for (int ni = 0; ni < 4; ni++) {
          const size_t idx = gr * CDIM + wn + ni * 16 + lr;
          O[idx] = f2bf(fmaxf(acc[mi][ni][r] + bv[ni], 0.f));
        }
      }
    }
  }
}

// ---------------- launch ----------------

extern "C" void kernel_launch(void* const* d_in, const int* in_sizes, int n_in,
                              void* d_out, int out_size, void* d_ws, size_t ws_size,
                              hipStream_t stream) {
  const float* x  = (const float*)d_in[0];
  const float* W1 = (const float*)d_in[1];
  const float* b1 = (const float*)d_in[2];
  const float* W2 = (const float*)d_in[3];
  const float* b2 = (const float*)d_in[4];
  const float* W3 = (const float*)d_in[5];
  const float* b3 = (const float*)d_in[6];
  const int* esp = (const int*)d_in[7];
  const int* etm = (const int*)d_in[8];

  const int Esp = in_sizes[7] / 2;
  const int Etm = in_sizes[8] / 2;
  const int B = in_sizes[0] / (NNODES * CDIM);
  const int M = B * NNODES;

  char* ws = (char*)d_ws;
  size_t woff = 0;
  auto alloc = [&](size_t bytes) -> void* {
    void* p = ws + woff;
    woff = (woff + bytes + 255) & ~(size_t)255;
    return p;
  };

  unsigned short* H   = (unsigned short*)alloc((size_t)M * CDIM * 2);  // 55.7 MB bf16
  unsigned short* Act = (unsigned short*)alloc((size_t)M * CDIM * 2);  // 55.7 MB bf16
  unsigned short* Wt  = (unsigned short*)alloc((size_t)3 * CDIM * CDIM * 2);
  int* zero_base = (int*)alloc((size_t)4 * NNODES * sizeof(int));
  int* cnt_sp = zero_base;
  int* cur_sp = zero_base + NNODES;
  int* cnt_tm = zero_base + 2 * NNODES;
  int* cur_tm = zero_base + 3 * NNODES;
  int* off_sp = (int*)alloc((NNODES + 1) * sizeof(int));
  int* off_tm = (int*)alloc((NNODES + 1) * sizeof(int));
  float* dinv_sp = (float*)alloc(NNODES * sizeof(float));
  float* dinv_tm = (float*)alloc(NNODES * sizeof(float));
  int*   src_sp = (int*)alloc((size_t)(Esp + NNODES) * sizeof(int));
  float* wgt_sp = (float*)alloc((size_t)(Esp + NNODES) * sizeof(float));
  int*   src_tm = (int*)alloc((size_t)(Etm + NNODES) * sizeof(int));
  float* wgt_tm = (float*)alloc((size_t)(Etm + NNODES) * sizeof(float));

  // graph preprocessing
  zero_kernel<<<(4 * NNODES + 255) / 256, 256, 0, stream>>>(zero_base, 4 * NNODES);
  transpose_kernel<<<256, 256, 0, stream>>>(W1, Wt);
  transpose_kernel<<<256, 256, 0, stream>>>(W2, Wt + CDIM * CDIM);
  transpose_kernel<<<256, 256, 0, stream>>>(W3, Wt + 2 * CDIM * CDIM);
  count_kernel<<<(Esp + 255) / 256, 256, 0, stream>>>(esp, Esp, cnt_sp);
  count_kernel<<<(Etm + 255) / 256, 256, 0, stream>>>(etm, Etm, cnt_tm);
  dinv_kernel<<<(NNODES + 255) / 256, 256, 0, stream>>>(cnt_sp, dinv_sp, NNODES);
  dinv_kernel<<<(NNODES + 255) / 256, 256, 0, stream>>>(cnt_tm, dinv_tm, NNODES);
  scan_kernel<<<1, 1024, 0, stream>>>(cnt_sp, NNODES, off_sp);
  scan_kernel<<<1, 1024, 0, stream>>>(cnt_tm, NNODES, off_tm);
  fill_kernel<<<(Esp + NNODES + 255) / 256, 256, 0, stream>>>(esp, Esp, NNODES, dinv_sp,
                                                              off_sp, cur_sp, src_sp, wgt_sp);
  fill_kernel<<<(Etm + NNODES + 255) / 256, 256, 0, stream>>>(etm, Etm, NNODES, dinv_tm,
                                                              off_tm, cur_tm, src_tm, wgt_tm);

  dim3 fgrid(M / 64);  // 1700

  // layer 1 (spatial): gather f32 x, GEMM W1, +b1, relu -> bf16 H
  fused_layer<true, false><<<fgrid, 256, 0, stream>>>(x, Wt, off_sp, src_sp, wgt_sp,
                                                      b1, nullptr, H);
  // layer 2 (temporal): gather bf16 H, GEMM W2, +b2, relu -> bf16 Act
  fused_layer<false, false><<<fgrid, 256, 0, stream>>>(H, Wt + CDIM * CDIM, off_tm, src_tm,
                                                       wgt_tm, b2, nullptr, Act);
  // layer 3 (spatial): gather bf16 Act, GEMM W3, +b3, +x, relu -> f32 d_out
  fused_layer<false, true><<<fgrid, 256, 0, stream>>>(Act, Wt + 2 * CDIM * CDIM, off_sp,
                                                      src_sp, wgt_sp, b3, x, d_out);
}

// Round 3
// 618.332 us; speedup vs baseline: 1.5050x; 1.5050x over previous
//
#include <hip/hip_runtime.h>

#define NNODES 1700
#define CDIM   256

typedef __attribute__((ext_vector_type(8))) short bf16x8;
typedef __attribute__((ext_vector_type(4))) float f32x4;

__device__ inline float bf2f(unsigned h) { return __uint_as_float(h << 16); }
__device__ inline unsigned short f2bf(float f) {
  unsigned u = __float_as_uint(f);
  u = (u + 0x7FFFu + ((u >> 16) & 1u)) >> 16;  // RNE
  return (unsigned short)u;
}

// ---------------- graph preprocessing ----------------

__global__ void zero_kernel(int* p, int n) {
  int i = blockIdx.x * blockDim.x + threadIdx.x;
  if (i < n) p[i] = 0;
}

// edge_index layout [2, E] row-major: sources [0..E), destinations [E..2E)
__global__ void count_kernel(const int* __restrict__ ei, int E, int* __restrict__ cnt) {
  int i = blockIdx.x * blockDim.x + threadIdx.x;
  if (i < E) atomicAdd(&cnt[ei[E + i]], 1);
}

__global__ void dinv_kernel(const int* __restrict__ cnt, float* __restrict__ dinv, int n) {
  int i = blockIdx.x * blockDim.x + threadIdx.x;
  if (i < n) dinv[i] = rsqrtf((float)(cnt[i] + 1));  // +1 self-loop; deg >= 1
}

// exclusive scan of (cnt[i]+1) over N=1700 -> off[0..N]; single block, 1024 thr, 2048 slots
__global__ __launch_bounds__(1024) void scan_kernel(const int* __restrict__ cnt, int n,
                                                    int* __restrict__ off) {
  __shared__ int s[2048];
  int t = threadIdx.x;
  for (int i = t; i < 2048; i += 1024) s[i] = (i < n) ? (cnt[i] + 1) : 0;
  for (int d = 1; d < 2048; d <<= 1) {
    __syncthreads();
    int idx = (t + 1) * (d << 1) - 1;
    if (idx < 2048) s[idx] += s[idx - d];
  }
  __syncthreads();
  if (t == 0) s[2047] = 0;
  for (int d = 1024; d >= 1; d >>= 1) {
    __syncthreads();
    int idx = (t + 1) * (d << 1) - 1;
    if (idx < 2048) { int tmp = s[idx - d]; s[idx - d] = s[idx]; s[idx] += tmp; }
  }
  __syncthreads();
  for (int i = t; i <= n; i += 1024) off[i] = s[i];
}

__global__ void fill_kernel(const int* __restrict__ ei, int E, int n,
                            const float* __restrict__ dinv, const int* __restrict__ off,
                            int* __restrict__ cursor, int* __restrict__ srcv,
                            float* __restrict__ wv) {
  int i = blockIdx.x * blockDim.x + threadIdx.x;
  if (i >= E + n) return;
  int s, d;
  if (i < E) { s = ei[i]; d = ei[E + i]; } else { s = d = i - E; }
  float w = dinv[s] * dinv[d];
  int p = atomicAdd(&cursor[d], 1);
  int idx = off[d] + p;
  srcv[idx] = s;
  wv[idx] = w;
}

// W f32 [k][n] row-major -> Wt bf16 [n][k]
__global__ void transpose_kernel(const float* __restrict__ W,
                                 unsigned short* __restrict__ Wt) {
  int i = blockIdx.x * 256 + threadIdx.x;  // 65536 elems
  int k = i >> 8, n = i & 255;
  Wt[n * 256 + k] = f2bf(W[i]);
}

// ---------------- fused GCN layer: out = epilogue( (A_hat @ X) @ W ) ------------------------
// Per block (64 rows): gather-aggregate 64 A-rows into LDS (4-row lockstep per wave, MLP~4),
// one __syncthreads, then barrier-free MFMA K-loop with B-fragments loaded straight from
// L2-resident Wt (no Bs LDS, no vmcnt pipeline). Epilogue: +bias, (+resid), relu, store.
// LDS = As only: 8 kchunks x (64*32 + 16 pad) shorts = 33 KB -> 4 blocks/CU, 16 waves/CU.
// Grid 1700, XCD-swizzled (m204 bijective) so each XCD sweeps contiguous batch slabs (L2 reuse).

#define ACH (64 * 32 + 16)  // padded kchunk stride (shorts); pad kills ds_write bank aliasing

template <bool AF32, bool FINAL>
__global__ __launch_bounds__(256, 4) void fused_layer(
    const void* __restrict__ Ap,            // X_prev: f32 [B,N,C] if AF32 else bf16
    const unsigned short* __restrict__ Wt,  // bf16 W^T [n][k]
    const int* __restrict__ off, const int* __restrict__ srcv,
    const float* __restrict__ wv, const float* __restrict__ bias,
    const float* __restrict__ resid,        // f32, FINAL only
    void* __restrict__ outp) {              // bf16 [M][C] or f32 (FINAL)
  __shared__ __align__(16) unsigned short As[8 * ACH];
  const int t = threadIdx.x;
  const int lane = t & 63;
  const int w = t >> 6;

  // XCD-aware bijective swizzle: consecutive swz on one XCD -> batch slab L2-resident
  const int nwg = gridDim.x;
  const int q = nwg >> 3, r = nwg & 7;
  const int xcd = blockIdx.x & 7, pos = blockIdx.x >> 3;
  const int swz = (xcd < r ? xcd * (q + 1) : r * (q + 1) + (xcd - r) * q) + pos;
  const int m0 = swz * 64;

  // ---- A-build: wave w owns rows [w*16, w*16+16), processed 4 at a time in lockstep ----
  const int cc = lane * 4;  // 4 channels per lane
  for (int q4 = 0; q4 < 4; q4++) {
    float ac[4][4] = {};          // [row j][ch]
    int ii[4], ee[4], sv_[4];
    float wt_[4];
    size_t base[4];
#pragma unroll
    for (int j = 0; j < 4; j++) {
      const int row = w * 16 + q4 * 4 + j;
      const int m = m0 + row;
      const int b = m / NNODES;
      const int n = m - b * NNODES;
      base[j] = (size_t)b * NNODES;
      ii[j] = off[n];
      ee[j] = off[n + 1];
      sv_[j] = srcv[ii[j]];       // deg >= 1 always (self-loop)
      wt_[j] = wv[ii[j]];
    }
    while ((ii[0] < ee[0]) | (ii[1] < ee[1]) | (ii[2] < ee[2]) | (ii[3] < ee[3])) {
      float4 vf[4];
      uint2 rw[4];
      // issue all 4 row-gathers (independent, stay in flight together)
#pragma unroll
      for (int j = 0; j < 4; j++) {
        if (ii[j] < ee[j]) {
          if (AF32)
            vf[j] = *(const float4*)((const float*)Ap + (base[j] + sv_[j]) * CDIM + cc);
          else
            rw[j] = *(const uint2*)((const unsigned short*)Ap + (base[j] + sv_[j]) * CDIM + cc);
        }
      }
      // issue next-edge metadata while gathers are in flight
      int sn[4]; float wn[4];
#pragma unroll
      for (int j = 0; j < 4; j++) {
        if (ii[j] + 1 < ee[j]) { sn[j] = srcv[ii[j] + 1]; wn[j] = wv[ii[j] + 1]; }
        else { sn[j] = 0; wn[j] = 0.f; }
      }
      // consume
#pragma unroll
      for (int j = 0; j < 4; j++) {
        if (ii[j] < ee[j]) {
          float4 v;
          if (AF32) v = vf[j];
          else {
            v.x = bf2f(rw[j].x & 0xffffu); v.y = bf2f(rw[j].x >> 16);
            v.z = bf2f(rw[j].y & 0xffffu); v.w = bf2f(rw[j].y >> 16);
          }
          const float wt = wt_[j];
          ac[j][0] += wt * v.x; ac[j][1] += wt * v.y;
          ac[j][2] += wt * v.z; ac[j][3] += wt * v.w;
          ii[j]++;
          sv_[j] = sn[j]; wt_[j] = wn[j];
        }
      }
    }
    // write 4 finished rows to As (bf16), layout [kchunk=cc>>5][row][cc&31] with pad
#pragma unroll
    for (int j = 0; j < 4; j++) {
      const int row = w * 16 + q4 * 4 + j;
      uint2 o;
      o.x = (unsigned)f2bf(ac[j][0]) | ((unsigned)f2bf(ac[j][1]) << 16);
      o.y = (unsigned)f2bf(ac[j][2]) | ((unsigned)f2bf(ac[j][3]) << 16);
      *(uint2*)&As[(cc >> 5) * ACH + row * 32 + (cc & 31)] = o;
    }
  }
  __syncthreads();

  // ---- barrier-free MFMA K-loop: A from LDS, B straight from L2-resident Wt ----
  const int wn = w * 64;
  const int lr = lane & 15;
  const int lk = (lane >> 4) * 8;
  f32x4 acc[4][4] = {};
  for (int K = 0; K < 8; K++) {
    bf16x8 b[4], a[4];
#pragma unroll
    for (int ni = 0; ni < 4; ni++)
      b[ni] = *(const bf16x8*)&Wt[(size_t)(wn + ni * 16 + lr) * CDIM + K * 32 + lk];
#pragma unroll
    for (int mi = 0; mi < 4; mi++)
      a[mi] = *(const bf16x8*)&As[K * ACH + (mi * 16 + lr) * 32 + lk];
#pragma unroll
    for (int mi = 0; mi < 4; mi++)
#pragma unroll
      for (int ni = 0; ni < 4; ni++)
        acc[mi][ni] = __builtin_amdgcn_mfma_f32_16x16x32_bf16(a[mi], b[ni], acc[mi][ni], 0, 0, 0);
  }

  // ---- epilogue ----
  float bv[4];
#pragma unroll
  for (int ni = 0; ni < 4; ni++) bv[ni] = bias[wn + ni * 16 + lr];
  const int orow = (lane >> 4) * 4;  // C/D: col=lane&15, row=(lane>>4)*4+r  [m89/m91]
#pragma unroll
  for (int mi = 0; mi < 4; mi++) {
#pragma unroll
    for (int r4 = 0; r4 < 4; r4++) {
      const size_t gr = (size_t)(m0 + mi * 16 + orow + r4);
      if (FINAL) {
        float* O = (float*)outp;
#pragma unroll
        for (int ni = 0; ni < 4; ni++) {
          const size_t idx = gr * CDIM + wn + ni * 16 + lr;
          float v = acc[mi][ni][r4] + bv[ni] + resid[idx];
          O[idx] = fmaxf(v, 0.f);
        }
      } else {
        unsigned short* O = (unsigned short*)outp;
#pragma unroll
        for (int ni = 0; ni < 4; ni++) {
          const size_t idx = gr * CDIM + wn + ni * 16 + lr;
          O[idx] = f2bf(fmaxf(acc[mi][ni][r4] + bv[ni], 0.f));
        }
      }
    }
  }
}

// ---------------- launch ----------------

extern "C" void kernel_launch(void* const* d_in, const int* in_sizes, int n_in,
                              void* d_out, int out_size, void* d_ws, size_t ws_size,
                              hipStream_t stream) {
  const float* x  = (const float*)d_in[0];
  const float* W1 = (const float*)d_in[1];
  const float* b1 = (const float*)d_in[2];
  const float* W2 = (const float*)d_in[3];
  const float* b2 = (const float*)d_in[4];
  const float* W3 = (const float*)d_in[5];
  const float* b3 = (const float*)d_in[6];
  const int* esp = (const int*)d_in[7];
  const int* etm = (const int*)d_in[8];

  const int Esp = in_sizes[7] / 2;
  const int Etm = in_sizes[8] / 2;
  const int B = in_sizes[0] / (NNODES * CDIM);
  const int M = B * NNODES;

  char* ws = (char*)d_ws;
  size_t woff = 0;
  auto alloc = [&](size_t bytes) -> void* {
    void* p = ws + woff;
    woff = (woff + bytes + 255) & ~(size_t)255;
    return p;
  };

  unsigned short* H   = (unsigned short*)alloc((size_t)M * CDIM * 2);  // 55.7 MB bf16
  unsigned short* Act = (unsigned short*)alloc((size_t)M * CDIM * 2);  // 55.7 MB bf16
  unsigned short* Wt  = (unsigned short*)alloc((size_t)3 * CDIM * CDIM * 2);
  int* zero_base = (int*)alloc((size_t)4 * NNODES * sizeof(int));
  int* cnt_sp = zero_base;
  int* cur_sp = zero_base + NNODES;
  int* cnt_tm = zero_base + 2 * NNODES;
  int* cur_tm = zero_base + 3 * NNODES;
  int* off_sp = (int*)alloc((NNODES + 1) * sizeof(int));
  int* off_tm = (int*)alloc((NNODES + 1) * sizeof(int));
  float* dinv_sp = (float*)alloc(NNODES * sizeof(float));
  float* dinv_tm = (float*)alloc(NNODES * sizeof(float));
  int*   src_sp = (int*)alloc((size_t)(Esp + NNODES) * sizeof(int));
  float* wgt_sp = (float*)alloc((size_t)(Esp + NNODES) * sizeof(float));
  int*   src_tm = (int*)alloc((size_t)(Etm + NNODES) * sizeof(int));
  float* wgt_tm = (float*)alloc((size_t)(Etm + NNODES) * sizeof(float));

  // graph preprocessing
  zero_kernel<<<(4 * NNODES + 255) / 256, 256, 0, stream>>>(zero_base, 4 * NNODES);
  transpose_kernel<<<256, 256, 0, stream>>>(W1, Wt);
  transpose_kernel<<<256, 256, 0, stream>>>(W2, Wt + CDIM * CDIM);
  transpose_kernel<<<256, 256, 0, stream>>>(W3, Wt + 2 * CDIM * CDIM);
  count_kernel<<<(Esp + 255) / 256, 256, 0, stream>>>(esp, Esp, cnt_sp);
  count_kernel<<<(Etm + 255) / 256, 256, 0, stream>>>(etm, Etm, cnt_tm);
  dinv_kernel<<<(NNODES + 255) / 256, 256, 0, stream>>>(cnt_sp, dinv_sp, NNODES);
  dinv_kernel<<<(NNODES + 255) / 256, 256, 0, stream>>>(cnt_tm, dinv_tm, NNODES);
  scan_kernel<<<1, 1024, 0, stream>>>(cnt_sp, NNODES, off_sp);
  scan_kernel<<<1, 1024, 0, stream>>>(cnt_tm, NNODES, off_tm);
  fill_kernel<<<(Esp + NNODES + 255) / 256, 256, 0, stream>>>(esp, Esp, NNODES, dinv_sp,
                                                              off_sp, cur_sp, src_sp, wgt_sp);
  fill_kernel<<<(Etm + NNODES + 255) / 256, 256, 0, stream>>>(etm, Etm, NNODES, dinv_tm,
                                                              off_tm, cur_tm, src_tm, wgt_tm);

  dim3 fgrid(M / 64);  // 1700

  // layer 1 (spatial): gather f32 x, GEMM W1, +b1, relu -> bf16 H
  fused_layer<true, false><<<fgrid, 256, 0, stream>>>(x, Wt, off_sp, src_sp, wgt_sp,
                                                      b1, nullptr, H);
  // layer 2 (temporal): gather bf16 H, GEMM W2, +b2, relu -> bf16 Act
  fused_layer<false, false><<<fgrid, 256, 0, stream>>>(H, Wt + CDIM * CDIM, off_tm, src_tm,
                                                       wgt_tm, b2, nullptr, Act);
  // layer 3 (spatial): gather bf16 Act, GEMM W3, +b3, +x, relu -> f32 d_out
  fused_layer<false, true><<<fgrid, 256, 0, stream>>>(Act, Wt + 2 * CDIM * CDIM, off_sp,
                                                      src_sp, wgt_sp, b3, x, d_out);
}

// Round 4
// 465.923 us; speedup vs baseline: 1.9974x; 1.3271x over previous
//
#include <hip/hip_runtime.h>

#define NNODES 1700
#define CDIM   256

typedef __attribute__((ext_vector_type(8))) short bf16x8;
typedef __attribute__((ext_vector_type(4))) float f32x4;

__device__ inline float bf2f(unsigned h) { return __uint_as_float(h << 16); }
__device__ inline unsigned short f2bf(float f) {
  unsigned u = __float_as_uint(f);
  u = (u + 0x7FFFu + ((u >> 16) & 1u)) >> 16;  // RNE
  return (unsigned short)u;
}

__device__ inline void async_copy16(const void* gsrc, void* ldst) {
  __builtin_amdgcn_global_load_lds(
      (const __attribute__((address_space(1))) unsigned int*)gsrc,
      (__attribute__((address_space(3))) unsigned int*)ldst,
      16, 0, 0);
}

// ---------------- graph preprocessing (merged: 12 launches -> 4) ----------------

// K1: zero counters/cursors + transpose 3 weight matrices (f32 [k][n] -> bf16 [n][k])
__global__ __launch_bounds__(256) void prep1(const float* __restrict__ W1,
                                             const float* __restrict__ W2,
                                             const float* __restrict__ W3,
                                             unsigned short* __restrict__ Wt,
                                             int* __restrict__ zb) {
  int i = blockIdx.x * 256 + threadIdx.x;
  if (i < 4 * NNODES) zb[i] = 0;
  if (i < 3 * 65536) {
    int wsel = i >> 16, e = i & 65535;
    const float* W = wsel == 0 ? W1 : (wsel == 1 ? W2 : W3);
    int k = e >> 8, n = e & 255;
    Wt[(wsel << 16) + n * 256 + k] = f2bf(W[e]);
  }
}

// K2: degree count for both graphs. edge_index [2,E]: sources [0..E), dests [E..2E)
__global__ __launch_bounds__(256) void prep2(const int* __restrict__ esp, int Esp,
                                             const int* __restrict__ etm, int Etm,
                                             int* __restrict__ cnt_sp,
                                             int* __restrict__ cnt_tm) {
  int i = blockIdx.x * 256 + threadIdx.x;
  if (i < Esp) {
    atomicAdd(&cnt_sp[esp[Esp + i]], 1);
  } else {
    int k = i - Esp;
    if (k < Etm) atomicAdd(&cnt_tm[etm[Etm + k]], 1);
  }
}

// K3: dinv + exclusive scan of (cnt+1) for both graphs; block 0 = spatial, block 1 = temporal
__global__ __launch_bounds__(1024) void prep3(const int* __restrict__ cnt_sp,
                                              float* __restrict__ dinv_sp,
                                              int* __restrict__ off_sp,
                                              const int* __restrict__ cnt_tm,
                                              float* __restrict__ dinv_tm,
                                              int* __restrict__ off_tm) {
  const int* cnt = blockIdx.x ? cnt_tm : cnt_sp;
  float* dinv = blockIdx.x ? dinv_tm : dinv_sp;
  int* off = blockIdx.x ? off_tm : off_sp;
  __shared__ int s[2048];
  int t = threadIdx.x;
  for (int i = t; i < NNODES; i += 1024) dinv[i] = rsqrtf((float)(cnt[i] + 1));
  for (int i = t; i < 2048; i += 1024) s[i] = (i < NNODES) ? (cnt[i] + 1) : 0;
  for (int d = 1; d < 2048; d <<= 1) {
    __syncthreads();
    int idx = (t + 1) * (d << 1) - 1;
    if (idx < 2048) s[idx] += s[idx - d];
  }
  __syncthreads();
  if (t == 0) s[2047] = 0;
  for (int d = 1024; d >= 1; d >>= 1) {
    __syncthreads();
    int idx = (t + 1) * (d << 1) - 1;
    if (idx < 2048) { int tmp = s[idx - d]; s[idx - d] = s[idx]; s[idx] += tmp; }
  }
  __syncthreads();
  for (int i = t; i <= NNODES; i += 1024) off[i] = s[i];
}

// K4: CSR fill for both graphs (order within a dest's list irrelevant: summed)
__global__ __launch_bounds__(256) void prep4(
    const int* __restrict__ esp, int Esp, const int* __restrict__ etm, int Etm,
    const float* __restrict__ dinv_sp, const int* __restrict__ off_sp,
    int* __restrict__ cur_sp, int* __restrict__ src_sp, float* __restrict__ wgt_sp,
    const float* __restrict__ dinv_tm, const int* __restrict__ off_tm,
    int* __restrict__ cur_tm, int* __restrict__ src_tm, float* __restrict__ wgt_tm) {
  int i = blockIdx.x * 256 + threadIdx.x;
  const int tot_sp = Esp + NNODES;
  if (i < tot_sp) {
    int s, d;
    if (i < Esp) { s = esp[i]; d = esp[Esp + i]; } else { s = d = i - Esp; }
    float w = dinv_sp[s] * dinv_sp[d];
    int p = atomicAdd(&cur_sp[d], 1);
    int idx = off_sp[d] + p;
    src_sp[idx] = s; wgt_sp[idx] = w;
  } else {
    int k = i - tot_sp;
    if (k < Etm + NNODES) {
      int s, d;
      if (k < Etm) { s = etm[k]; d = etm[Etm + k]; } else { s = d = k - Etm; }
      float w = dinv_tm[s] * dinv_tm[d];
      int p = atomicAdd(&cur_tm[d], 1);
      int idx = off_tm[d] + p;
      src_tm[idx] = s; wgt_tm[idx] = w;
    }
  }
}

// ---------------- aggregation: Xa[b,n,:] = sum_e w_e * X[b,src_e,:]  (pure, no bias/relu) ----
// (A_hat X) computed BEFORE the GEMM: associativity A_hat(XW) = (A_hat X)W.
// grid (NNODES, B/8), block 256: 8 batches x 32 lanes x 8 channels. High occupancy
// (54K waves) is what gets this gather pattern to ~4 TB/s (R1 evidence).
// 2-way edge unroll keeps 2 row-gathers in flight per thread.

template <bool SRCF32>
__global__ __launch_bounds__(256) void agg_kernel(const void* __restrict__ Xp,
                                                  const int* __restrict__ off,
                                                  const int* __restrict__ srcv,
                                                  const float* __restrict__ wv,
                                                  unsigned short* __restrict__ Xa) {
  const int n = blockIdx.x;
  const int b = blockIdx.y * 8 + (threadIdx.x >> 5);
  const int c = (threadIdx.x & 31) * 8;
  const int beg = off[n], end = off[n + 1];
  const size_t base = (size_t)b * NNODES;

  float a0 = 0.f, a1 = 0.f, a2 = 0.f, a3 = 0.f;
  float a4 = 0.f, a5 = 0.f, a6 = 0.f, a7 = 0.f;
  for (int i = beg; i < end; i += 2) {
    int s0 = srcv[i];
    float w0 = wv[i];
    const bool two = (i + 1 < end);
    int i1 = two ? i + 1 : i;
    int s1 = srcv[i1];
    float w1 = two ? wv[i1] : 0.f;  // weight-0 duplicate gather on odd tail (values finite)
    if (SRCF32) {
      const float* X = (const float*)Xp;
      const float* p0 = X + (base + s0) * CDIM + c;
      const float* p1 = X + (base + s1) * CDIM + c;
      float4 u0 = *(const float4*)p0, u1 = *(const float4*)(p0 + 4);
      float4 v0 = *(const float4*)p1, v1 = *(const float4*)(p1 + 4);
      a0 += w0 * u0.x + w1 * v0.x; a1 += w0 * u0.y + w1 * v0.y;
      a2 += w0 * u0.z + w1 * v0.z; a3 += w0 * u0.w + w1 * v0.w;
      a4 += w0 * u1.x + w1 * v1.x; a5 += w0 * u1.y + w1 * v1.y;
      a6 += w0 * u1.z + w1 * v1.z; a7 += w0 * u1.w + w1 * v1.w;
    } else {
      const unsigned short* X = (const unsigned short*)Xp;
      uint4 u = *(const uint4*)(X + (base + s0) * CDIM + c);
      uint4 v = *(const uint4*)(X + (base + s1) * CDIM + c);
      a0 += w0 * bf2f(u.x & 0xffffu) + w1 * bf2f(v.x & 0xffffu);
      a1 += w0 * bf2f(u.x >> 16)     + w1 * bf2f(v.x >> 16);
      a2 += w0 * bf2f(u.y & 0xffffu) + w1 * bf2f(v.y & 0xffffu);
      a3 += w0 * bf2f(u.y >> 16)     + w1 * bf2f(v.y >> 16);
      a4 += w0 * bf2f(u.z & 0xffffu) + w1 * bf2f(v.z & 0xffffu);
      a5 += w0 * bf2f(u.z >> 16)     + w1 * bf2f(v.z >> 16);
      a6 += w0 * bf2f(u.w & 0xffffu) + w1 * bf2f(v.w & 0xffffu);
      a7 += w0 * bf2f(u.w >> 16)     + w1 * bf2f(v.w >> 16);
    }
  }
  bf16x8 ov;
  ov[0] = (short)f2bf(a0); ov[1] = (short)f2bf(a1);
  ov[2] = (short)f2bf(a2); ov[3] = (short)f2bf(a3);
  ov[4] = (short)f2bf(a4); ov[5] = (short)f2bf(a5);
  ov[6] = (short)f2bf(a6); ov[7] = (short)f2bf(a7);
  *(bf16x8*)(Xa + (base + n) * CDIM + c) = ov;
}

// ---------------- GEMM: out = epilogue( Xa[M][256] @ W ) ; Xa bf16, Wt bf16 W^T [n][k] -----
// 128x256 tile (full N), 8 waves (2x4, 64x64 each), BK=32, 8 K-steps.
// Counted-vmcnt pipeline: 3 LDS buffers, depth-2 prefetch, 1 raw barrier/step, vmcnt never 0
// in steady state (proven R1 template, unchanged). Epilogue: +bias, relu; FINAL: +resid f32,
// f32 out (absorbs what was the 68us FINAL-agg pass).

template <int K>
__device__ __forceinline__ void kstep(const unsigned short* __restrict__ asrc,
                                      const unsigned short* __restrict__ bsrc,
                                      unsigned short (&As)[3][128 * 32],
                                      unsigned short (&Bs)[3][256 * 32],
                                      int t, int wm, int wn, int lr, int lk,
                                      f32x4 (&acc)[4][4]) {
  // stage K issued 2 steps ago; leave {K+1, K+2} (3 loads each) in flight
  if constexpr (K < 7) {
    asm volatile("s_waitcnt vmcnt(3)" ::: "memory");
  } else {
    asm volatile("s_waitcnt vmcnt(0)" ::: "memory");
  }
  __builtin_amdgcn_s_barrier();  // raw barrier: no auto vmcnt(0) drain
  if constexpr (K + 2 < 8) {
    constexpr int S = K + 2;
    async_copy16(asrc + S * 32, &As[S % 3][t * 8]);
    async_copy16(bsrc + S * 32, &Bs[S % 3][t * 8]);
    async_copy16(bsrc + 128 * CDIM + S * 32, &Bs[S % 3][4096 + t * 8]);
  }
  bf16x8 a[4], b[4];
#pragma unroll
  for (int i = 0; i < 4; i++)
    a[i] = *(const bf16x8*)&As[K % 3][(wm + i * 16 + lr) * 32 + lk];
#pragma unroll
  for (int i = 0; i < 4; i++)
    b[i] = *(const bf16x8*)&Bs[K % 3][(wn + i * 16 + lr) * 32 + lk];
#pragma unroll
  for (int mi = 0; mi < 4; mi++)
#pragma unroll
    for (int ni = 0; ni < 4; ni++)
      acc[mi][ni] = __builtin_amdgcn_mfma_f32_16x16x32_bf16(a[mi], b[ni], acc[mi][ni], 0, 0, 0);
}

template <bool FINAL>
__global__ __launch_bounds__(512, 4) void gemm_n256(const unsigned short* __restrict__ A,
                                                    const unsigned short* __restrict__ Wt,
                                                    const float* __restrict__ bias,
                                                    const float* __restrict__ resid,
                                                    void* __restrict__ outp) {
  __shared__ __align__(16) unsigned short As[3][128 * 32];  // 24 KB
  __shared__ __align__(16) unsigned short Bs[3][256 * 32];  // 48 KB
  const int m0 = blockIdx.x * 128;
  const int t = threadIdx.x;
  const int lane = t & 63;
  const int w = t >> 6;
  const int wm = (w & 1) * 64;
  const int wn = (w >> 1) * 64;
  const int lr = lane & 15;
  const int lk = (lane >> 4) * 8;

  // staging: 16B chunk c covers row c>>2, k-off (c&3)*8. A: chunks 0..511 (t).
  // B: chunks t (rows 0..127) and t+512 (rows 128..255).
  const unsigned short* asrc = A + (size_t)(m0 + (t >> 2)) * CDIM + (t & 3) * 8;
  const unsigned short* bsrc = Wt + (size_t)(t >> 2) * CDIM + (t & 3) * 8;

  f32x4 acc[4][4] = {};

#pragma unroll
  for (int s = 0; s < 2; s++) {  // prologue: stages 0,1 in flight
    async_copy16(asrc + s * 32, &As[s][t * 8]);
    async_copy16(bsrc + s * 32, &Bs[s][t * 8]);
    async_copy16(bsrc + 128 * CDIM + s * 32, &Bs[s][4096 + t * 8]);
  }

  kstep<0>(asrc, bsrc, As, Bs, t, wm, wn, lr, lk, acc);
  kstep<1>(asrc, bsrc, As, Bs, t, wm, wn, lr, lk, acc);
  kstep<2>(asrc, bsrc, As, Bs, t, wm, wn, lr, lk, acc);
  kstep<3>(asrc, bsrc, As, Bs, t, wm, wn, lr, lk, acc);
  kstep<4>(asrc, bsrc, As, Bs, t, wm, wn, lr, lk, acc);
  kstep<5>(asrc, bsrc, As, Bs, t, wm, wn, lr, lk, acc);
  kstep<6>(asrc, bsrc, As, Bs, t, wm, wn, lr, lk, acc);
  kstep<7>(asrc, bsrc, As, Bs, t, wm, wn, lr, lk, acc);

  // ---- epilogue: +bias, relu, (FINAL: +resid, f32 out) ----
  float bv[4];
#pragma unroll
  for (int ni = 0; ni < 4; ni++) bv[ni] = bias[wn + ni * 16 + lr];
  const int orow = (lane >> 4) * 4;  // C/D: col=lane&15, row=(lane>>4)*4+r  [m89/m91]
#pragma unroll
  for (int mi = 0; mi < 4; mi++) {
#pragma unroll
    for (int ni = 0; ni < 4; ni++) {
#pragma unroll
      for (int r = 0; r < 4; r++) {
        const size_t gr = (size_t)(m0 + wm + mi * 16 + orow + r);
        const size_t idx = gr * CDIM + wn + ni * 16 + lr;
        float v = acc[mi][ni][r] + bv[ni];
        if (FINAL) {
          v += resid[idx];
          ((float*)outp)[idx] = fmaxf(v, 0.f);
        } else {
          ((unsigned short*)outp)[idx] = f2bf(fmaxf(v, 0.f));
        }
      }
    }
  }
}

// ---------------- launch ----------------

extern "C" void kernel_launch(void* const* d_in, const int* in_sizes, int n_in,
                              void* d_out, int out_size, void* d_ws, size_t ws_size,
                              hipStream_t stream) {
  const float* x  = (const float*)d_in[0];
  const float* W1 = (const float*)d_in[1];
  const float* b1 = (const float*)d_in[2];
  const float* W2 = (const float*)d_in[3];
  const float* b2 = (const float*)d_in[4];
  const float* W3 = (const float*)d_in[5];
  const float* b3 = (const float*)d_in[6];
  const int* esp = (const int*)d_in[7];
  const int* etm = (const int*)d_in[8];

  const int Esp = in_sizes[7] / 2;
  const int Etm = in_sizes[8] / 2;
  const int B = in_sizes[0] / (NNODES * CDIM);
  const int M = B * NNODES;

  char* ws = (char*)d_ws;
  size_t woff = 0;
  auto alloc = [&](size_t bytes) -> void* {
    void* p = ws + woff;
    woff = (woff + bytes + 255) & ~(size_t)255;
    return p;
  };

  unsigned short* H   = (unsigned short*)alloc((size_t)M * CDIM * 2);  // 55.7 MB bf16
  unsigned short* Act = (unsigned short*)alloc((size_t)M * CDIM * 2);  // 55.7 MB bf16
  unsigned short* Wt  = (unsigned short*)alloc((size_t)3 * CDIM * CDIM * 2);
  int* zero_base = (int*)alloc((size_t)4 * NNODES * sizeof(int));
  int* cnt_sp = zero_base;
  int* cur_sp = zero_base + NNODES;
  int* cnt_tm = zero_base + 2 * NNODES;
  int* cur_tm = zero_base + 3 * NNODES;
  int* off_sp = (int*)alloc((NNODES + 1) * sizeof(int));
  int* off_tm = (int*)alloc((NNODES + 1) * sizeof(int));
  float* dinv_sp = (float*)alloc(NNODES * sizeof(float));
  float* dinv_tm = (float*)alloc(NNODES * sizeof(float));
  int*   src_sp = (int*)alloc((size_t)(Esp + NNODES) * sizeof(int));
  float* wgt_sp = (float*)alloc((size_t)(Esp + NNODES) * sizeof(float));
  int*   src_tm = (int*)alloc((size_t)(Etm + NNODES) * sizeof(int));
  float* wgt_tm = (float*)alloc((size_t)(Etm + NNODES) * sizeof(float));

  // graph preprocessing: 4 launches
  prep1<<<(3 * 65536 + 255) / 256, 256, 0, stream>>>(W1, W2, W3, Wt, zero_base);
  prep2<<<(Esp + Etm + 255) / 256, 256, 0, stream>>>(esp, Esp, etm, Etm, cnt_sp, cnt_tm);
  prep3<<<2, 1024, 0, stream>>>(cnt_sp, dinv_sp, off_sp, cnt_tm, dinv_tm, off_tm);
  prep4<<<(Esp + Etm + 2 * NNODES + 255) / 256, 256, 0, stream>>>(
      esp, Esp, etm, Etm, dinv_sp, off_sp, cur_sp, src_sp, wgt_sp,
      dinv_tm, off_tm, cur_tm, src_tm, wgt_tm);

  dim3 agrid(NNODES, B / 8);
  dim3 ggrid(M / 128);

  // layer 1 (spatial): Xa1 = A_hat x (f32 gather); out1 = relu(Xa1 W1 + b1) -> bf16 H
  agg_kernel<true><<<agrid, 256, 0, stream>>>(x, off_sp, src_sp, wgt_sp, Act);
  gemm_n256<false><<<ggrid, 512, 0, stream>>>(Act, Wt, b1, nullptr, H);
  // layer 2 (temporal)
  agg_kernel<false><<<agrid, 256, 0, stream>>>(H, off_tm, src_tm, wgt_tm, Act);
  gemm_n256<false><<<ggrid, 512, 0, stream>>>(Act, Wt + CDIM * CDIM, b2, nullptr, H);
  // layer 3 (spatial) + residual + relu -> f32 d_out
  agg_kernel<false><<<agrid, 256, 0, stream>>>(H, off_sp, src_sp, wgt_sp, Act);
  gemm_n256<true><<<ggrid, 512, 0, stream>>>(Act, Wt + 2 * CDIM * CDIM, b3, x, d_out);
}

// Round 5
// 437.513 us; speedup vs baseline: 2.1270x; 1.0649x over previous
//
#include <hip/hip_runtime.h>

#define NNODES 1700
#define CDIM   256

typedef __attribute__((ext_vector_type(8))) short bf16x8;
typedef __attribute__((ext_vector_type(4))) float f32x4;

__device__ inline float bf2f(unsigned h) { return __uint_as_float(h << 16); }
__device__ inline unsigned short f2bf(float f) {
  unsigned u = __float_as_uint(f);
  u = (u + 0x7FFFu + ((u >> 16) & 1u)) >> 16;  // RNE
  return (unsigned short)u;
}

__device__ inline void async_copy16(const void* gsrc, void* ldst) {
  __builtin_amdgcn_global_load_lds(
      (const __attribute__((address_space(1))) unsigned int*)gsrc,
      (__attribute__((address_space(3))) unsigned int*)ldst,
      16, 0, 0);
}

// ---------------- graph preprocessing (4 launches) ----------------

// K1: zero counters/cursors + transpose 3 weight matrices (f32 [k][n] -> bf16 [n][k])
__global__ __launch_bounds__(256) void prep1(const float* __restrict__ W1,
                                             const float* __restrict__ W2,
                                             const float* __restrict__ W3,
                                             unsigned short* __restrict__ Wt,
                                             int* __restrict__ zb) {
  int i = blockIdx.x * 256 + threadIdx.x;
  if (i < 4 * NNODES) zb[i] = 0;
  if (i < 3 * 65536) {
    int wsel = i >> 16, e = i & 65535;
    const float* W = wsel == 0 ? W1 : (wsel == 1 ? W2 : W3);
    int k = e >> 8, n = e & 255;
    Wt[(wsel << 16) + n * 256 + k] = f2bf(W[e]);
  }
}

// K2: degree count for both graphs. edge_index [2,E]: sources [0..E), dests [E..2E)
__global__ __launch_bounds__(256) void prep2(const int* __restrict__ esp, int Esp,
                                             const int* __restrict__ etm, int Etm,
                                             int* __restrict__ cnt_sp,
                                             int* __restrict__ cnt_tm) {
  int i = blockIdx.x * 256 + threadIdx.x;
  if (i < Esp) {
    atomicAdd(&cnt_sp[esp[Esp + i]], 1);
  } else {
    int k = i - Esp;
    if (k < Etm) atomicAdd(&cnt_tm[etm[Etm + k]], 1);
  }
}

// K3: dinv + exclusive scan of (cnt+1) for both graphs; block 0 = spatial, block 1 = temporal
__global__ __launch_bounds__(1024) void prep3(const int* __restrict__ cnt_sp,
                                              float* __restrict__ dinv_sp,
                                              int* __restrict__ off_sp,
                                              const int* __restrict__ cnt_tm,
                                              float* __restrict__ dinv_tm,
                                              int* __restrict__ off_tm) {
  const int* cnt = blockIdx.x ? cnt_tm : cnt_sp;
  float* dinv = blockIdx.x ? dinv_tm : dinv_sp;
  int* off = blockIdx.x ? off_tm : off_sp;
  __shared__ int s[2048];
  int t = threadIdx.x;
  for (int i = t; i < NNODES; i += 1024) dinv[i] = rsqrtf((float)(cnt[i] + 1));
  for (int i = t; i < 2048; i += 1024) s[i] = (i < NNODES) ? (cnt[i] + 1) : 0;
  for (int d = 1; d < 2048; d <<= 1) {
    __syncthreads();
    int idx = (t + 1) * (d << 1) - 1;
    if (idx < 2048) s[idx] += s[idx - d];
  }
  __syncthreads();
  if (t == 0) s[2047] = 0;
  for (int d = 1024; d >= 1; d >>= 1) {
    __syncthreads();
    int idx = (t + 1) * (d << 1) - 1;
    if (idx < 2048) { int tmp = s[idx - d]; s[idx - d] = s[idx]; s[idx] += tmp; }
  }
  __syncthreads();
  for (int i = t; i <= NNODES; i += 1024) off[i] = s[i];
}

// K4: CSR fill for both graphs (order within a dest's list irrelevant: summed)
__global__ __launch_bounds__(256) void prep4(
    const int* __restrict__ esp, int Esp, const int* __restrict__ etm, int Etm,
    const float* __restrict__ dinv_sp, const int* __restrict__ off_sp,
    int* __restrict__ cur_sp, int* __restrict__ src_sp, float* __restrict__ wgt_sp,
    const float* __restrict__ dinv_tm, const int* __restrict__ off_tm,
    int* __restrict__ cur_tm, int* __restrict__ src_tm, float* __restrict__ wgt_tm) {
  int i = blockIdx.x * 256 + threadIdx.x;
  const int tot_sp = Esp + NNODES;
  if (i < tot_sp) {
    int s, d;
    if (i < Esp) { s = esp[i]; d = esp[Esp + i]; } else { s = d = i - Esp; }
    float w = dinv_sp[s] * dinv_sp[d];
    int p = atomicAdd(&cur_sp[d], 1);
    int idx = off_sp[d] + p;
    src_sp[idx] = s; wgt_sp[idx] = w;
  } else {
    int k = i - tot_sp;
    if (k < Etm + NNODES) {
      int s, d;
      if (k < Etm) { s = etm[k]; d = etm[Etm + k]; } else { s = d = k - Etm; }
      float w = dinv_tm[s] * dinv_tm[d];
      int p = atomicAdd(&cur_tm[d], 1);
      int idx = off_tm[d] + p;
      src_tm[idx] = s; wgt_tm[idx] = w;
    }
  }
}

// ---------------- aggregation: Xa[b,n,:] = sum_e w_e * X[b,src_e,:]  (pure, no bias/relu) ----
// grid (NNODES, B/8), block 256: 8 batches x 32 lanes x 8 channels. High occupancy hides
// gather latency (measured ~4 TB/s L2-fill). 2-way edge unroll keeps 2 gathers in flight.

template <bool SRCF32>
__global__ __launch_bounds__(256) void agg_kernel(const void* __restrict__ Xp,
                                                  const int* __restrict__ off,
                                                  const int* __restrict__ srcv,
                                                  const float* __restrict__ wv,
                                                  unsigned short* __restrict__ Xa) {
  const int n = blockIdx.x;
  const int b = blockIdx.y * 8 + (threadIdx.x >> 5);
  const int c = (threadIdx.x & 31) * 8;
  const int beg = off[n], end = off[n + 1];
  const size_t base = (size_t)b * NNODES;

  float a0 = 0.f, a1 = 0.f, a2 = 0.f, a3 = 0.f;
  float a4 = 0.f, a5 = 0.f, a6 = 0.f, a7 = 0.f;
  for (int i = beg; i < end; i += 2) {
    int s0 = srcv[i];
    float w0 = wv[i];
    const bool two = (i + 1 < end);
    int i1 = two ? i + 1 : i;
    int s1 = srcv[i1];
    float w1 = two ? wv[i1] : 0.f;  // weight-0 duplicate gather on odd tail (values finite)
    if (SRCF32) {
      const float* X = (const float*)Xp;
      const float* p0 = X + (base + s0) * CDIM + c;
      const float* p1 = X + (base + s1) * CDIM + c;
      float4 u0 = *(const float4*)p0, u1 = *(const float4*)(p0 + 4);
      float4 v0 = *(const float4*)p1, v1 = *(const float4*)(p1 + 4);
      a0 += w0 * u0.x + w1 * v0.x; a1 += w0 * u0.y + w1 * v0.y;
      a2 += w0 * u0.z + w1 * v0.z; a3 += w0 * u0.w + w1 * v0.w;
      a4 += w0 * u1.x + w1 * v1.x; a5 += w0 * u1.y + w1 * v1.y;
      a6 += w0 * u1.z + w1 * v1.z; a7 += w0 * u1.w + w1 * v1.w;
    } else {
      const unsigned short* X = (const unsigned short*)Xp;
      uint4 u = *(const uint4*)(X + (base + s0) * CDIM + c);
      uint4 v = *(const uint4*)(X + (base + s1) * CDIM + c);
      a0 += w0 * bf2f(u.x & 0xffffu) + w1 * bf2f(v.x & 0xffffu);
      a1 += w0 * bf2f(u.x >> 16)     + w1 * bf2f(v.x >> 16);
      a2 += w0 * bf2f(u.y & 0xffffu) + w1 * bf2f(v.y & 0xffffu);
      a3 += w0 * bf2f(u.y >> 16)     + w1 * bf2f(v.y >> 16);
      a4 += w0 * bf2f(u.z & 0xffffu) + w1 * bf2f(v.z & 0xffffu);
      a5 += w0 * bf2f(u.z >> 16)     + w1 * bf2f(v.z >> 16);
      a6 += w0 * bf2f(u.w & 0xffffu) + w1 * bf2f(v.w & 0xffffu);
      a7 += w0 * bf2f(u.w >> 16)     + w1 * bf2f(v.w >> 16);
    }
  }
  bf16x8 ov;
  ov[0] = (short)f2bf(a0); ov[1] = (short)f2bf(a1);
  ov[2] = (short)f2bf(a2); ov[3] = (short)f2bf(a3);
  ov[4] = (short)f2bf(a4); ov[5] = (short)f2bf(a5);
  ov[6] = (short)f2bf(a6); ov[7] = (short)f2bf(a7);
  *(bf16x8*)(Xa + (base + n) * CDIM + c) = ov;
}

// ---------------- GEMM: out = epilogue( Xa[M][256] @ W ) --------------------------------------
// Redesign for latency tolerance: BM=128 x BN=64, 256 thr (4 waves 2x2), wave-tile 64x32
// -> acc 32 regs/wave (~5 waves/SIMD), LDS 24 KB double-buffer -> ~5 blocks/CU = 5
// INDEPENDENT pipeline phases per CU (vs 2 big lockstepped blocks before).
// Per step: [vmcnt(3) stage K ready][bar][ds_read K][lgkm0][bar][issue stage K+2][8 MFMA].
// Exact counted vmcnt (3 loads/thread/stage), never drained mid-loop.
// Grid (850 m x 4 n), n-fastest + bijective XCD swizzle (3400%8==0): the 4 n-siblings of an
// m-slab co-run on one XCD -> A re-reads hit L2; HBM sees A ~once.

template <int K>
__device__ __forceinline__ void kstep(const unsigned short* __restrict__ asrc,
                                      const unsigned short* __restrict__ bsrc,
                                      unsigned short (&As)[2][128 * 32],
                                      unsigned short (&Bs)[2][64 * 32],
                                      int t, int wm, int wn, int lr, int lk,
                                      f32x4 (&acc)[4][2]) {
  if constexpr (K < 7) {
    asm volatile("s_waitcnt vmcnt(3)" ::: "memory");  // stage K done; K+1 (3) in flight
  } else {
    asm volatile("s_waitcnt vmcnt(0)" ::: "memory");
  }
  __builtin_amdgcn_s_barrier();  // stage K visible to all waves
  bf16x8 a[4], b[2];
#pragma unroll
  for (int i = 0; i < 4; i++)
    a[i] = *(const bf16x8*)&As[K & 1][(wm + i * 16 + lr) * 32 + lk];
#pragma unroll
  for (int i = 0; i < 2; i++)
    b[i] = *(const bf16x8*)&Bs[K & 1][(wn + i * 16 + lr) * 32 + lk];
  asm volatile("s_waitcnt lgkmcnt(0)" ::: "memory");  // reads landed in regs
  __builtin_amdgcn_sched_barrier(0);                  // rule #18 guard
  __builtin_amdgcn_s_barrier();  // all waves done reading buf K&1 -> safe to overwrite
  if constexpr (K + 2 < 8) {
    constexpr int S = K + 2;  // into buf (K+2)&1 == K&1
    async_copy16(asrc + S * 32, &As[S & 1][t * 8]);
    async_copy16(asrc + (size_t)64 * CDIM + S * 32, &As[S & 1][2048 + t * 8]);
    async_copy16(bsrc + S * 32, &Bs[S & 1][t * 8]);
  }
#pragma unroll
  for (int mi = 0; mi < 4; mi++)
#pragma unroll
    for (int ni = 0; ni < 2; ni++)
      acc[mi][ni] = __builtin_amdgcn_mfma_f32_16x16x32_bf16(a[mi], b[ni], acc[mi][ni], 0, 0, 0);
}

template <bool FINAL>
__global__ __launch_bounds__(256, 5) void gemm_t64(const unsigned short* __restrict__ A,
                                                   const unsigned short* __restrict__ Wt,
                                                   const float* __restrict__ bias,
                                                   const float* __restrict__ resid,
                                                   void* __restrict__ outp) {
  __shared__ __align__(16) unsigned short As[2][128 * 32];  // 16 KB
  __shared__ __align__(16) unsigned short Bs[2][64 * 32];   //  8 KB
  const int t = threadIdx.x;
  const int lane = t & 63;
  const int w = t >> 6;
  const int wm = (w & 1) * 64;
  const int wn = (w >> 1) * 32;
  const int lr = lane & 15;
  const int lk = (lane >> 4) * 8;

  // bijective XCD swizzle (grid % 8 == 0): XCD x runs swz in [x*chunk, (x+1)*chunk)
  const int chunk = gridDim.x >> 3;
  const int swz = (blockIdx.x & 7) * chunk + (blockIdx.x >> 3);
  const int m0 = (swz >> 2) * 128;  // n-fastest: 4 n-siblings adjacent -> same XCD
  const int n0 = (swz & 3) * 64;

  // staging: 16B chunk c: row c>>2, k-off (c&3)*8. As: chunks t (rows 0..63), t+256
  // (rows 64..127). Bs: chunk t (rows 0..63).
  const unsigned short* asrc = A + (size_t)(m0 + (t >> 2)) * CDIM + (t & 3) * 8;
  const unsigned short* bsrc = Wt + (size_t)(n0 + (t >> 2)) * CDIM + (t & 3) * 8;

  f32x4 acc[4][2] = {};

#pragma unroll
  for (int s = 0; s < 2; s++) {  // prologue: stages 0,1 in flight (3 loads each)
    async_copy16(asrc + s * 32, &As[s][t * 8]);
    async_copy16(asrc + (size_t)64 * CDIM + s * 32, &As[s][2048 + t * 8]);
    async_copy16(bsrc + s * 32, &Bs[s][t * 8]);
  }

  kstep<0>(asrc, bsrc, As, Bs, t, wm, wn, lr, lk, acc);
  kstep<1>(asrc, bsrc, As, Bs, t, wm, wn, lr, lk, acc);
  kstep<2>(asrc, bsrc, As, Bs, t, wm, wn, lr, lk, acc);
  kstep<3>(asrc, bsrc, As, Bs, t, wm, wn, lr, lk, acc);
  kstep<4>(asrc, bsrc, As, Bs, t, wm, wn, lr, lk, acc);
  kstep<5>(asrc, bsrc, As, Bs, t, wm, wn, lr, lk, acc);
  kstep<6>(asrc, bsrc, As, Bs, t, wm, wn, lr, lk, acc);
  kstep<7>(asrc, bsrc, As, Bs, t, wm, wn, lr, lk, acc);

  // ---- epilogue: +bias, relu, (FINAL: +resid, f32 out) ----
  float bv[2];
#pragma unroll
  for (int ni = 0; ni < 2; ni++) bv[ni] = bias[n0 + wn + ni * 16 + lr];
  const int orow = (lane >> 4) * 4;  // C/D: col=lane&15, row=(lane>>4)*4+r  [m89/m91]
#pragma unroll
  for (int mi = 0; mi < 4; mi++) {
#pragma unroll
    for (int ni = 0; ni < 2; ni++) {
#pragma unroll
      for (int r = 0; r < 4; r++) {
        const size_t gr = (size_t)(m0 + wm + mi * 16 + orow + r);
        const size_t idx = gr * CDIM + n0 + wn + ni * 16 + lr;
        float v = acc[mi][ni][r] + bv[ni];
        if (FINAL) {
          v += resid[idx];
          ((float*)outp)[idx] = fmaxf(v, 0.f);
        } else {
          ((unsigned short*)outp)[idx] = f2bf(fmaxf(v, 0.f));
        }
      }
    }
  }
}

// ---------------- launch ----------------

extern "C" void kernel_launch(void* const* d_in, const int* in_sizes, int n_in,
                              void* d_out, int out_size, void* d_ws, size_t ws_size,
                              hipStream_t stream) {
  const float* x  = (const float*)d_in[0];
  const float* W1 = (const float*)d_in[1];
  const float* b1 = (const float*)d_in[2];
  const float* W2 = (const float*)d_in[3];
  const float* b2 = (const float*)d_in[4];
  const float* W3 = (const float*)d_in[5];
  const float* b3 = (const float*)d_in[6];
  const int* esp = (const int*)d_in[7];
  const int* etm = (const int*)d_in[8];

  const int Esp = in_sizes[7] / 2;
  const int Etm = in_sizes[8] / 2;
  const int B = in_sizes[0] / (NNODES * CDIM);
  const int M = B * NNODES;

  char* ws = (char*)d_ws;
  size_t woff = 0;
  auto alloc = [&](size_t bytes) -> void* {
    void* p = ws + woff;
    woff = (woff + bytes + 255) & ~(size_t)255;
    return p;
  };

  unsigned short* H   = (unsigned short*)alloc((size_t)M * CDIM * 2);  // 55.7 MB bf16
  unsigned short* Act = (unsigned short*)alloc((size_t)M * CDIM * 2);  // 55.7 MB bf16
  unsigned short* Wt  = (unsigned short*)alloc((size_t)3 * CDIM * CDIM * 2);
  int* zero_base = (int*)alloc((size_t)4 * NNODES * sizeof(int));
  int* cnt_sp = zero_base;
  int* cur_sp = zero_base + NNODES;
  int* cnt_tm = zero_base + 2 * NNODES;
  int* cur_tm = zero_base + 3 * NNODES;
  int* off_sp = (int*)alloc((NNODES + 1) * sizeof(int));
  int* off_tm = (int*)alloc((NNODES + 1) * sizeof(int));
  float* dinv_sp = (float*)alloc(NNODES * sizeof(float));
  float* dinv_tm = (float*)alloc(NNODES * sizeof(float));
  int*   src_sp = (int*)alloc((size_t)(Esp + NNODES) * sizeof(int));
  float* wgt_sp = (float*)alloc((size_t)(Esp + NNODES) * sizeof(float));
  int*   src_tm = (int*)alloc((size_t)(Etm + NNODES) * sizeof(int));
  float* wgt_tm = (float*)alloc((size_t)(Etm + NNODES) * sizeof(float));

  // graph preprocessing: 4 launches
  prep1<<<(3 * 65536 + 255) / 256, 256, 0, stream>>>(W1, W2, W3, Wt, zero_base);
  prep2<<<(Esp + Etm + 255) / 256, 256, 0, stream>>>(esp, Esp, etm, Etm, cnt_sp, cnt_tm);
  prep3<<<2, 1024, 0, stream>>>(cnt_sp, dinv_sp, off_sp, cnt_tm, dinv_tm, off_tm);
  prep4<<<(Esp + Etm + 2 * NNODES + 255) / 256, 256, 0, stream>>>(
      esp, Esp, etm, Etm, dinv_sp, off_sp, cur_sp, src_sp, wgt_sp,
      dinv_tm, off_tm, cur_tm, src_tm, wgt_tm);

  dim3 agrid(NNODES, B / 8);
  dim3 ggrid(4 * (M / 128));  // 3400: (850 m-blocks) x (4 n-blocks), n fastest

  // layer 1 (spatial): Xa1 = A_hat x (f32 gather); out1 = relu(Xa1 W1 + b1) -> bf16 H
  agg_kernel<true><<<agrid, 256, 0, stream>>>(x, off_sp, src_sp, wgt_sp, Act);
  gemm_t64<false><<<ggrid, 256, 0, stream>>>(Act, Wt, b1, nullptr, H);
  // layer 2 (temporal)
  agg_kernel<false><<<agrid, 256, 0, stream>>>(H, off_tm, src_tm, wgt_tm, Act);
  gemm_t64<false><<<ggrid, 256, 0, stream>>>(Act, Wt + CDIM * CDIM, b2, nullptr, H);
  // layer 3 (spatial) + residual + relu -> f32 d_out
  agg_kernel<false><<<agrid, 256, 0, stream>>>(H, off_sp, src_sp, wgt_sp, Act);
  gemm_t64<true><<<ggrid, 256, 0, stream>>>(Act, Wt + 2 * CDIM * CDIM, b3, x, d_out);
}